// Round 4
// baseline (1300.612 us; speedup 1.0000x reference)
//
#include <hip/hip_runtime.h>

typedef unsigned int uu32;
typedef unsigned short uu16;

#define NN 14      // nodes
#define FD 24      // SEQ / feature dim
#define HD 64      // GAT hidden
#define NE 70      // 56 edges + 14 self loops
#define BB 32768   // batch
#define SPW 4      // samples per wave
#define WPB 4      // waves per block
#define K1_BLOCKS 2048   // BB / (WPB*SPW)
#define K2_BLOCKS 1792   // NN * BB / 256

__device__ __forceinline__ float bf2f(uu16 h) {
    return __uint_as_float(((uu32)h) << 16);
}
__device__ __forceinline__ uu16 f2b(float f) {   // RNE float->bf16
    uu32 u = __float_as_uint(f);
    return (uu16)((u + 0x7fffu + ((u >> 16) & 1u)) >> 16);
}

// Distinguish a bf16 buffer from a float32 buffer of random weights.
// bf16 mode: each dword's LOW u16 is a bf16; its sign-masked high byte is
// the exponent byte, confined to ~[0x28,0x44] for magnitudes 1e-26..1e4.
// f32 mode: that byte is low mantissa bits -> ~uniform (hit prob ~0.23).
// 32-dword vote, threshold 24: misclassification odds ~1e-11.
__device__ __forceinline__ int sniff_f32(const void* p) {
    const uu32* d = (const uu32*)p;
    int hits = 0;
    for (int i = 0; i < 32; i++) {
        uu32 hb = (d[i] >> 8) & 0x7fu;
        if (hb >= 0x28u && hb <= 0x44u) hits++;
    }
    return (hits >= 24) ? 0 : 1;   // 1 = float32, 0 = bf16
}

struct RB {
    const uu16* h; const float* f; int m;
    __device__ __forceinline__ void init(const void* p, int mode) {
        h = (const uu16*)p; f = (const float*)p; m = mode;
    }
    __device__ __forceinline__ float ld(size_t i) const {
        return m ? f[i] : bf2f(h[i]);
    }
};
__device__ __forceinline__ void sto(void* p, int m, size_t i, float v) {
    if (m) ((float*)p)[i] = v;
    else   ((uu16*)p)[i] = f2b(v);
}

// GAT stage: G = conv2(elu(conv1(x))) -> Gout[14][B][24] (Gout == d_out;
// the MLP kernel rewrites d_out in place afterwards).
__global__ __launch_bounds__(256) void stg_gat_k(
    const void* xp, const int* ei, const void* W1p, const void* as1p,
    const void* ad1p, const void* b1p, const void* W2p, const void* as2p,
    const void* ad2p, const void* b2p, void* Gout) {
    __shared__ float XS[WPB][NN * FD];    // 336/wave
    __shared__ float H1S[WPB][NN * 65];   // pad 65: conflict-free dots
    __shared__ float A1S[WPB][NN * 65];
    __shared__ float H2S[WPB][NN * 25];
    __shared__ float PS[WPB][NN * 16];
    __shared__ float sdS[WPB][2 * NN];
    __shared__ float a1S[2 * HD];
    __shared__ float a2S[2 * FD];
    __shared__ int esS[NE], edS[NE];

    const int mode = sniff_f32(W1p);
    RB X;   X.init(xp, mode);
    RB W1;  W1.init(W1p, mode);
    RB AS1; AS1.init(as1p, mode);
    RB AD1; AD1.init(ad1p, mode);
    RB B1;  B1.init(b1p, mode);
    RB W2;  W2.init(W2p, mode);
    RB AS2; AS2.init(as2p, mode);
    RB AD2; AD2.init(ad2p, mode);
    RB B2;  B2.init(b2p, mode);

    const int tid = threadIdx.x;
    const int wv = tid >> 6;
    const int lane = tid & 63;
    float* XSw = XS[wv];
    float* H1w = H1S[wv];
    float* A1w = A1S[wv];
    float* H2w = H2S[wv];
    float* Pw = PS[wv];
    float* sdw = sdS[wv];

    if (tid < 2 * HD) a1S[tid] = (tid < HD) ? AS1.ld(tid) : AD1.ld(tid - HD);
    if (tid < 2 * FD) a2S[tid] = (tid < FD) ? AS2.ld(tid) : AD2.ld(tid - FD);
    // edge staging: robust to int64 (lo/hi dword pairs) or int32 delivery
    if (tid < 56) {
        int e64 = 1;
        for (int i = 0; i < 8; i++)
            if (ei[2 * i + 1] != 0 || (uu32)ei[2 * i] >= (uu32)NN) e64 = 0;
        esS[tid] = e64 ? ei[2 * tid] : ei[tid];
        edS[tid] = e64 ? ei[112 + 2 * tid] : ei[56 + tid];
    } else if (tid < NE) {
        esS[tid] = tid - 56;   // self loops
        edS[tid] = tid - 56;
    }

    // per-lane resident weights
    float w1r[FD];
    for (int f = 0; f < FD; f++) w1r[f] = W1.ld(f * HD + lane);
    const float b1r = B1.ld(lane);
    const int f2 = lane % FD;
    const int g2 = lane / FD;      // 0,1 active for 24-wide stages
    float w2r[HD];
    for (int k = 0; k < HD; k++) w2r[k] = W2.ld(k * FD + f2);
    const float b2r = B2.ld(f2);
    __syncthreads();

    const int gw = blockIdx.x * WPB + wv;
    for (int t = 0; t < SPW; t++) {
        const size_t b = (size_t)gw * SPW + t;
        // ---- stage X[b] (f-major 24x14) -> XS[n][f] fp32 ----
        for (int q = 0; q < 6; q++) {
            int e = lane + 64 * q;
            if (e < NN * FD)
                XSw[(e % NN) * FD + (e / NN)] = X.ld(b * (NN * FD) + e);
        }
        __syncthreads();
        // ---- H1 = X @ W1 : lane owns hidden column `lane` ----
        float acc[NN];
        for (int n = 0; n < NN; n++) acc[n] = 0.0f;
        for (int f = 0; f < FD; f++) {
            float wf = w1r[f];
            for (int n = 0; n < NN; n++)
                acc[n] = fmaf(XSw[n * FD + f], wf, acc[n]);
        }
        for (int n = 0; n < NN; n++) H1w[n * 65 + lane] = acc[n];
        __syncthreads();
        // ---- src/dst attention dots (28 lanes, stride-65) ----
        if (lane < 2 * NN) {
            int n2 = lane % NN, v = lane / NN;
            float s = 0.0f;
            for (int q = 0; q < HD; q++)
                s = fmaf(H1w[n2 * 65 + q], a1S[v * HD + q], s);
            sdw[v * NN + n2] = s;
        }
        __syncthreads();
        // ---- per-dst softmax -> P rows (owner lane loops all edges) ----
        if (lane < NN) {
            const int n = lane;
            for (int k = 0; k < 16; k++) Pw[n * 16 + k] = 0.0f;
            float mx = -1e30f;
            for (int e = 0; e < NE; e++)
                if (edS[e] == n) {
                    float a = sdw[esS[e]] + sdw[NN + n];
                    a = a > 0.0f ? a : 0.2f * a;
                    if (a > mx) mx = a;
                }
            float s = 0.0f;
            for (int e = 0; e < NE; e++)
                if (edS[e] == n) {
                    float a = sdw[esS[e]] + sdw[NN + n];
                    a = a > 0.0f ? a : 0.2f * a;
                    s += __expf(a - mx);
                }
            float inv = 1.0f / s;
            for (int e = 0; e < NE; e++)
                if (edS[e] == n) {
                    float a = sdw[esS[e]] + sdw[NN + n];
                    a = a > 0.0f ? a : 0.2f * a;
                    Pw[n * 16 + esS[e]] += __expf(a - mx) * inv;
                }
        }
        __syncthreads();
        // ---- A1 = ELU(P @ H1 + b1) ----
        for (int n = 0; n < NN; n++) {
            float a = 0.0f;
            for (int k = 0; k < NN; k++)
                a = fmaf(Pw[n * 16 + k], H1w[k * 65 + lane], a);
            a += b1r;
            A1w[n * 65 + lane] = a > 0.0f ? a : (__expf(a) - 1.0f);
        }
        __syncthreads();
        // ---- H2 = A1 @ W2 : lane (g2,f2) covers 7 nodes ----
        if (g2 < 2) {
            for (int i = 0; i < 7; i++) {
                int n = g2 + 2 * i;
                float a = 0.0f;
                for (int k = 0; k < HD; k++)
                    a = fmaf(A1w[n * 65 + k], w2r[k], a);
                H2w[n * 25 + f2] = a;
            }
        }
        __syncthreads();
        // ---- conv2 src/dst dots (28 lanes, stride-25) ----
        if (lane < 2 * NN) {
            int n2 = lane % NN, v = lane / NN;
            float s = 0.0f;
            for (int q = 0; q < FD; q++)
                s = fmaf(H2w[n2 * 25 + q], a2S[v * FD + q], s);
            sdw[v * NN + n2] = s;
        }
        __syncthreads();
        // ---- softmax2 -> P ----
        if (lane < NN) {
            const int n = lane;
            for (int k = 0; k < 16; k++) Pw[n * 16 + k] = 0.0f;
            float mx = -1e30f;
            for (int e = 0; e < NE; e++)
                if (edS[e] == n) {
                    float a = sdw[esS[e]] + sdw[NN + n];
                    a = a > 0.0f ? a : 0.2f * a;
                    if (a > mx) mx = a;
                }
            float s = 0.0f;
            for (int e = 0; e < NE; e++)
                if (edS[e] == n) {
                    float a = sdw[esS[e]] + sdw[NN + n];
                    a = a > 0.0f ? a : 0.2f * a;
                    s += __expf(a - mx);
                }
            float inv = 1.0f / s;
            for (int e = 0; e < NE; e++)
                if (edS[e] == n) {
                    float a = sdw[esS[e]] + sdw[NN + n];
                    a = a > 0.0f ? a : 0.2f * a;
                    Pw[n * 16 + esS[e]] += __expf(a - mx) * inv;
                }
        }
        __syncthreads();
        // ---- G = P2 @ H2 + b2 -> d_out [14][B][24] ----
        if (g2 < 2) {
            for (int i = 0; i < 7; i++) {
                int n = g2 + 2 * i;
                float a = 0.0f;
                for (int k = 0; k < NN; k++)
                    a = fmaf(Pw[n * 16 + k], H2w[k * 25 + f2], a);
                a += b2r;
                sto(Gout, mode, ((size_t)n * BB + b) * FD + f2, a);
            }
        }
        __syncthreads();   // protect reused LDS before next sample
    }
}

// MLP stage, in place on d_out. Each thread reads exactly the 24 G values
// of its own (node, sample) row and overwrites the same 24 slots -> no
// intra- or inter-thread hazard.
__global__ __launch_bounds__(256) void stg_mlp_k(
    const void* f1wp, const void* f1bp, const void* f2wp, const void* f2bp,
    void* gio) {
    __shared__ float W1L[FD * HD];
    __shared__ float W2L[HD * FD];
    __shared__ float B1L[HD];
    __shared__ float B2L[FD];

    const int mode = sniff_f32(f1wp);
    RB F1;  F1.init(f1wp, mode);
    RB F1b; F1b.init(f1bp, mode);
    RB F2;  F2.init(f2wp, mode);
    RB F2b; F2b.init(f2bp, mode);
    RB G;   G.init(gio, mode);

    const int t = threadIdx.x;
    const int n = blockIdx.x >> 7;             // 128 blocks per node
    const int b0 = (blockIdx.x & 127) * 256;

    for (int i = t; i < FD * HD; i += 256) {
        W1L[i] = F1.ld((size_t)n * (FD * HD) + i);   // fc1_w[n][f][j]
        W2L[i] = F2.ld((size_t)n * (HD * FD) + i);   // fc2_w[n][j][f]
    }
    if (t < HD) B1L[t] = F1b.ld(n * HD + t);
    if (t < FD) B2L[t] = F2b.ld(n * FD + t);
    __syncthreads();

    const size_t base = ((size_t)n * BB + b0 + t) * FD;
    float g[FD], o[FD];
    for (int f = 0; f < FD; f++) g[f] = G.ld(base + f);
    for (int f = 0; f < FD; f++) o[f] = B2L[f];
    for (int j = 0; j < HD; j++) {
        float h = B1L[j];
        for (int f = 0; f < FD; f++)
            h = fmaf(g[f], W1L[f * HD + j], h);
        h = h > 0.0f ? h : 0.0f;               // ReLU
        for (int f = 0; f < FD; f++)
            o[f] = fmaf(h, W2L[j * FD + f], o[f]);
    }
    for (int f = 0; f < FD; f++) sto(gio, mode, base + f, o[f]);
}

extern "C" void kernel_launch(void* const* d_in, const int* in_sizes, int n_in,
                              void* d_out, int out_size, void* d_ws, size_t ws_size,
                              hipStream_t stream) {
    (void)in_sizes; (void)n_in; (void)out_size; (void)d_ws; (void)ws_size;
    const void* x    = d_in[0];
    const int*  ei   = (const int*)d_in[1];
    const void* W1   = d_in[2];
    const void* as1  = d_in[3];
    const void* ad1  = d_in[4];
    const void* b1   = d_in[5];
    const void* W2   = d_in[6];
    const void* as2  = d_in[7];
    const void* ad2  = d_in[8];
    const void* b2   = d_in[9];
    const void* fc1w = d_in[10];
    const void* fc1b = d_in[11];
    const void* fc2w = d_in[12];
    const void* fc2b = d_in[13];

    stg_gat_k<<<dim3(K1_BLOCKS), dim3(256), 0, stream>>>(
        x, ei, W1, as1, ad1, b1, W2, as2, ad2, b2, d_out);
    stg_mlp_k<<<dim3(K2_BLOCKS), dim3(256), 0, stream>>>(
        fc1w, fc1b, fc2w, fc2b, d_out);
}

// Round 5
// 346.504 us; speedup vs baseline: 3.7535x; 3.7535x over previous
//
#include <hip/hip_runtime.h>

typedef unsigned int uu32;

#define NN 14      // nodes
#define FD 24      // SEQ / feature dim
#define HD 64      // GAT hidden
#define NE 70      // 56 edges + 14 self loops
#define BB 32768   // batch
#define SPW 4      // samples per wave
#define WPB 4      // waves per block
#define K1_BLOCKS (BB / (WPB * SPW))   // 2048
#define K2_BLOCKS (NN * (BB / 256))    // 1792
#define HAP 68     // padded row stride for H1/A1 (16B-aligned rows)
#define H2P 28     // padded row stride for H2 (16B-aligned rows)

// GAT stage: G = conv2(elu(conv1(x))) -> Gout[14][B][24] f32 (Gout == d_out;
// the MLP kernel rewrites d_out in place afterwards — proven green in r4).
__global__ __launch_bounds__(256) void gat_k(
    const float* __restrict__ x, const int* __restrict__ ei,
    const float* __restrict__ W1, const float* __restrict__ as1,
    const float* __restrict__ ad1, const float* __restrict__ b1,
    const float* __restrict__ W2, const float* __restrict__ as2,
    const float* __restrict__ ad2, const float* __restrict__ b2,
    float* __restrict__ Gout) {
    __shared__ __align__(16) float XS[WPB][NN * FD];    // 336
    __shared__ __align__(16) float HA[WPB][NN * HAP];   // H1 then A1 (952)
    __shared__ __align__(16) float H2S[WPB][NN * H2P];  // 392
    __shared__ __align__(16) float PS[WPB][256];        // unnormalized exp rows
    __shared__ float sdS[WPB][2 * NN];                  // src/dst dots
    __shared__ float smS[WPB][NN];                      // per-dst exp sums
    __shared__ __align__(16) float a1S[2 * HD];
    __shared__ __align__(16) float a2S[2 * FD];
    __shared__ int esS[NE], edS[NE];

    const int tid = threadIdx.x;
    const int wv = tid >> 6;
    const int lane = tid & 63;
    float* XSw = XS[wv];
    float* HAw = HA[wv];
    float* H2w = H2S[wv];
    float* Pw = PS[wv];
    float* sdw = sdS[wv];
    float* smw = smS[wv];

    if (tid < 2 * HD) a1S[tid] = (tid < HD) ? as1[tid] : ad1[tid - HD];
    if (tid < 2 * FD) a2S[tid] = (tid < FD) ? as2[tid] : ad2[tid - FD];
    // edge staging: robust to int64 (lo/hi dword pairs) or int32 delivery
    if (tid < 56) {
        int e64 = 1;
        for (int i = 0; i < 8; i++)
            if (ei[2 * i + 1] != 0 || (uu32)ei[2 * i] >= (uu32)NN) e64 = 0;
        esS[tid] = e64 ? ei[2 * tid] : ei[tid];
        edS[tid] = e64 ? ei[112 + 2 * tid] : ei[56 + tid];
    } else if (tid < NE) {
        esS[tid] = tid - 56;   // self loops
        edS[tid] = tid - 56;
    }

    // per-lane resident weights
    float w1r[FD];
#pragma unroll
    for (int f = 0; f < FD; f++) w1r[f] = W1[f * HD + lane];
    const float b1r = b1[lane];
    const int f2 = lane % FD;
    const int g2 = lane / FD;      // 0,1 active for 24-wide stages
    float w2r[HD];
#pragma unroll
    for (int k = 0; k < HD; k++) w2r[k] = W2[k * FD + f2];
    const float b2r = b2[f2];
    __syncthreads();
    // edge ownership: edge0 = lane (0..63); lanes 0..5 also own 64..69
    const bool ex = (lane < NE - 64);
    const int s0 = esS[lane], d0 = edS[lane];
    const int s1 = esS[ex ? 64 + lane : 0], d1 = edS[ex ? 64 + lane : 0];

    const int gw = blockIdx.x * WPB + wv;
    for (int t = 0; t < SPW; t++) {
        const size_t b = (size_t)gw * SPW + t;
        // ---- 1. stage X[b] (f-major [24][14]) -> XS[n][f], float4 loads ----
        const float4* xb4 = (const float4*)(x + b * (NN * FD));
        {
            float4 v = xb4[lane];
            int e = 4 * lane;
            XSw[(e % NN) * FD + (e / NN)] = v.x; e++;
            XSw[(e % NN) * FD + (e / NN)] = v.y; e++;
            XSw[(e % NN) * FD + (e / NN)] = v.z; e++;
            XSw[(e % NN) * FD + (e / NN)] = v.w;
            if (lane < 20) {
                v = xb4[64 + lane];
                e = 256 + 4 * lane;
                XSw[(e % NN) * FD + (e / NN)] = v.x; e++;
                XSw[(e % NN) * FD + (e / NN)] = v.y; e++;
                XSw[(e % NN) * FD + (e / NN)] = v.z; e++;
                XSw[(e % NN) * FD + (e / NN)] = v.w;
            }
        }
        __syncthreads();
        // ---- 2. H1 = X @ W1 (lane owns hidden col `lane`), write to HA ----
        float acc[NN];
#pragma unroll
        for (int n = 0; n < NN; n++) acc[n] = 0.0f;
#pragma unroll
        for (int k = 0; k < 6; k++) {
#pragma unroll
            for (int n = 0; n < NN; n++) {
                float4 xv = *(const float4*)&XSw[n * FD + 4 * k];   // broadcast
                acc[n] = fmaf(xv.x, w1r[4 * k + 0], acc[n]);
                acc[n] = fmaf(xv.y, w1r[4 * k + 1], acc[n]);
                acc[n] = fmaf(xv.z, w1r[4 * k + 2], acc[n]);
                acc[n] = fmaf(xv.w, w1r[4 * k + 3], acc[n]);
            }
        }
#pragma unroll
        for (int n = 0; n < NN; n++) HAw[n * HAP + lane] = acc[n];
        __syncthreads();
        // ---- 3. src/dst dots (28 lanes) + zero P/sums ----
        if (lane < 2 * NN) {
            const int v = (lane >= NN) ? 1 : 0;
            const int n2 = lane - v * NN;
            float s = 0.0f;
#pragma unroll
            for (int k = 0; k < 16; k++) {
                float4 h4 = *(const float4*)&HAw[n2 * HAP + 4 * k];
                float4 a4 = *(const float4*)&a1S[v * HD + 4 * k];
                s = fmaf(h4.x, a4.x, s); s = fmaf(h4.y, a4.y, s);
                s = fmaf(h4.z, a4.z, s); s = fmaf(h4.w, a4.w, s);
            }
            sdw[v * NN + n2] = s;
        }
        *(float4*)&Pw[lane * 4] = make_float4(0.f, 0.f, 0.f, 0.f);
        if (lane < NN) smw[lane] = 0.0f;
        __syncthreads();
        // ---- 4. softmax1 (shift-invariant, no max pass: |alpha| << 88) ----
        {
            float a = sdw[s0] + sdw[NN + d0];
            a = a > 0.0f ? a : 0.2f * a;               // leaky_relu(0.2)
            float e0 = __expf(a);
            atomicAdd(&smw[d0], e0);
            atomicAdd(&Pw[d0 * 16 + s0], e0);          // unnormalized
            if (ex) {
                a = sdw[s1] + sdw[NN + d1];
                a = a > 0.0f ? a : 0.2f * a;
                float e1 = __expf(a);
                atomicAdd(&smw[d1], e1);
                atomicAdd(&Pw[d1 * 16 + s1], e1);
            }
        }
        __syncthreads();
        // ---- 5. A1 = ELU(P @ H1 / sum + b1); H1 from regs; write to HA ----
        float acc2[NN];
#pragma unroll
        for (int n = 0; n < NN; n++) {
            float a = 0.0f;
#pragma unroll
            for (int k4 = 0; k4 < 3; k4++) {
                float4 p4 = *(const float4*)&Pw[n * 16 + 4 * k4];   // broadcast
                a = fmaf(p4.x, acc[4 * k4 + 0], a);
                a = fmaf(p4.y, acc[4 * k4 + 1], a);
                a = fmaf(p4.z, acc[4 * k4 + 2], a);
                a = fmaf(p4.w, acc[4 * k4 + 3], a);
            }
            float4 p4 = *(const float4*)&Pw[n * 16 + 12];
            a = fmaf(p4.x, acc[12], a);
            a = fmaf(p4.y, acc[13], a);
            a = __fdividef(a, smw[n]) + b1r;
            acc2[n] = a > 0.0f ? a : (__expf(a) - 1.0f);   // ELU
        }
#pragma unroll
        for (int n = 0; n < NN; n++) HAw[n * HAP + lane] = acc2[n];
        __syncthreads();
        // ---- 6. H2 = A1 @ W2 : lane (g2,f2) covers 7 nodes ----
        if (g2 < 2) {
#pragma unroll
            for (int i = 0; i < 7; i++) {
                const int n = g2 + 2 * i;
                float a = 0.0f;
#pragma unroll
                for (int k4 = 0; k4 < 16; k4++) {
                    float4 v4 = *(const float4*)&HAw[n * HAP + 4 * k4];
                    a = fmaf(v4.x, w2r[4 * k4 + 0], a);
                    a = fmaf(v4.y, w2r[4 * k4 + 1], a);
                    a = fmaf(v4.z, w2r[4 * k4 + 2], a);
                    a = fmaf(v4.w, w2r[4 * k4 + 3], a);
                }
                H2w[n * H2P + f2] = a;
            }
        }
        __syncthreads();
        // ---- 7. conv2 dots (28 lanes) + zero P/sums ----
        if (lane < 2 * NN) {
            const int v = (lane >= NN) ? 1 : 0;
            const int n2 = lane - v * NN;
            float s = 0.0f;
#pragma unroll
            for (int q = 0; q < 6; q++) {
                float4 h4 = *(const float4*)&H2w[n2 * H2P + 4 * q];
                float4 a4 = *(const float4*)&a2S[v * FD + 4 * q];
                s = fmaf(h4.x, a4.x, s); s = fmaf(h4.y, a4.y, s);
                s = fmaf(h4.z, a4.z, s); s = fmaf(h4.w, a4.w, s);
            }
            sdw[v * NN + n2] = s;
        }
        *(float4*)&Pw[lane * 4] = make_float4(0.f, 0.f, 0.f, 0.f);
        if (lane < NN) smw[lane] = 0.0f;
        __syncthreads();
        // ---- 8. softmax2 ----
        {
            float a = sdw[s0] + sdw[NN + d0];
            a = a > 0.0f ? a : 0.2f * a;
            float e0 = __expf(a);
            atomicAdd(&smw[d0], e0);
            atomicAdd(&Pw[d0 * 16 + s0], e0);
            if (ex) {
                a = sdw[s1] + sdw[NN + d1];
                a = a > 0.0f ? a : 0.2f * a;
                float e1 = __expf(a);
                atomicAdd(&smw[d1], e1);
                atomicAdd(&Pw[d1 * 16 + s1], e1);
            }
        }
        __syncthreads();
        // ---- 9. G = P2 @ H2 / sum + b2 -> d_out [14][B][24] ----
        if (g2 < 2) {
            float h2c[NN];
#pragma unroll
            for (int k = 0; k < NN; k++) h2c[k] = H2w[k * H2P + f2];
#pragma unroll
            for (int i = 0; i < 7; i++) {
                const int n = g2 + 2 * i;
                float a = 0.0f;
#pragma unroll
                for (int k4 = 0; k4 < 3; k4++) {
                    float4 p4 = *(const float4*)&Pw[n * 16 + 4 * k4];
                    a = fmaf(p4.x, h2c[4 * k4 + 0], a);
                    a = fmaf(p4.y, h2c[4 * k4 + 1], a);
                    a = fmaf(p4.z, h2c[4 * k4 + 2], a);
                    a = fmaf(p4.w, h2c[4 * k4 + 3], a);
                }
                float4 p4 = *(const float4*)&Pw[n * 16 + 12];
                a = fmaf(p4.x, h2c[12], a);
                a = fmaf(p4.y, h2c[13], a);
                Gout[((size_t)n * BB + b) * FD + f2] =
                    __fdividef(a, smw[n]) + b2r;
            }
        }
        __syncthreads();   // protect reused LDS before next sample
    }
}

// MLP stage, in place on d_out. Each thread owns one (node, sample) row:
// reads its 24 G values, overwrites the same 24 slots. float4 throughout.
__global__ __launch_bounds__(256) void mlp_k(
    const float* __restrict__ fc1w, const float* __restrict__ fc1b,
    const float* __restrict__ fc2w, const float* __restrict__ fc2b,
    float* gio) {
    __shared__ __align__(16) float W1L[FD * HD];
    __shared__ __align__(16) float W2L[HD * FD];
    __shared__ float B1L[HD];
    __shared__ float B2L[FD];

    const int t = threadIdx.x;
    const int n = blockIdx.x >> 7;             // 128 blocks per node
    const int b0 = (blockIdx.x & 127) * 256;

    const float4* w1p = (const float4*)(fc1w + (size_t)n * (FD * HD));
    const float4* w2p = (const float4*)(fc2w + (size_t)n * (HD * FD));
    for (int i = t; i < 384; i += 256) {
        *(float4*)&W1L[4 * i] = w1p[i];
        *(float4*)&W2L[4 * i] = w2p[i];
    }
    if (t < HD) B1L[t] = fc1b[n * HD + t];
    if (t < FD) B2L[t] = fc2b[n * FD + t];
    __syncthreads();

    const size_t base = ((size_t)n * BB + b0 + t) * FD;
    float g[FD], o[FD];
#pragma unroll
    for (int q = 0; q < 6; q++)
        *(float4*)&g[4 * q] = *(const float4*)&gio[base + 4 * q];
#pragma unroll
    for (int f = 0; f < FD; f++) o[f] = B2L[f];

#pragma unroll
    for (int j4 = 0; j4 < 16; j4++) {
        float h0 = B1L[4 * j4 + 0], h1 = B1L[4 * j4 + 1];
        float h2 = B1L[4 * j4 + 2], h3 = B1L[4 * j4 + 3];
#pragma unroll
        for (int f = 0; f < FD; f++) {
            float4 w4 = *(const float4*)&W1L[f * HD + 4 * j4];   // broadcast
            h0 = fmaf(g[f], w4.x, h0);
            h1 = fmaf(g[f], w4.y, h1);
            h2 = fmaf(g[f], w4.z, h2);
            h3 = fmaf(g[f], w4.w, h3);
        }
        h0 = fmaxf(h0, 0.f); h1 = fmaxf(h1, 0.f);
        h2 = fmaxf(h2, 0.f); h3 = fmaxf(h3, 0.f);
        float hv[4] = {h0, h1, h2, h3};
#pragma unroll
        for (int u2 = 0; u2 < 4; u2++) {
            const int j = 4 * j4 + u2;
#pragma unroll
            for (int f4 = 0; f4 < 6; f4++) {
                float4 w4 = *(const float4*)&W2L[j * FD + 4 * f4];   // broadcast
                o[4 * f4 + 0] = fmaf(hv[u2], w4.x, o[4 * f4 + 0]);
                o[4 * f4 + 1] = fmaf(hv[u2], w4.y, o[4 * f4 + 1]);
                o[4 * f4 + 2] = fmaf(hv[u2], w4.z, o[4 * f4 + 2]);
                o[4 * f4 + 3] = fmaf(hv[u2], w4.w, o[4 * f4 + 3]);
            }
        }
    }
#pragma unroll
    for (int q = 0; q < 6; q++)
        *(float4*)&gio[base + 4 * q] = *(const float4*)&o[4 * q];
}

extern "C" void kernel_launch(void* const* d_in, const int* in_sizes, int n_in,
                              void* d_out, int out_size, void* d_ws, size_t ws_size,
                              hipStream_t stream) {
    (void)in_sizes; (void)n_in; (void)out_size; (void)d_ws; (void)ws_size;
    const float* x    = (const float*)d_in[0];
    const int*   ei   = (const int*)d_in[1];
    const float* W1   = (const float*)d_in[2];
    const float* as1  = (const float*)d_in[3];
    const float* ad1  = (const float*)d_in[4];
    const float* b1   = (const float*)d_in[5];
    const float* W2   = (const float*)d_in[6];
    const float* as2  = (const float*)d_in[7];
    const float* ad2  = (const float*)d_in[8];
    const float* b2   = (const float*)d_in[9];
    const float* fc1w = (const float*)d_in[10];
    const float* fc1b = (const float*)d_in[11];
    const float* fc2w = (const float*)d_in[12];
    const float* fc2b = (const float*)d_in[13];
    float* gio = (float*)d_out;   // G staged in d_out, MLP rewrites in place

    gat_k<<<dim3(K1_BLOCKS), dim3(256), 0, stream>>>(
        x, ei, W1, as1, ad1, b1, W2, as2, ad2, b2, gio);
    mlp_k<<<dim3(K2_BLOCKS), dim3(256), 0, stream>>>(
        fc1w, fc1b, fc2w, fc2b, gio);
}